// Round 1
// baseline (219.154 us; speedup 1.0000x reference)
//
#include <hip/hip_runtime.h>

typedef __bf16 bf16x8 __attribute__((ext_vector_type(8)));
typedef float f32x4 __attribute__((ext_vector_type(4)));
typedef unsigned short us4 __attribute__((ext_vector_type(4)));

#define SCALE 0.17677669529663687f

__device__ __forceinline__ unsigned short f2bf(float f) {
    union { float f; unsigned u; } v; v.f = f;
    unsigned r = v.u + 0x7FFFu + ((v.u >> 16) & 1u);
    return (unsigned short)(r >> 16);
}

// ---------------- prep: transpose+bf16 weights, build rel-pos bias table ----------------
__global__ void wa_prep(const float* __restrict__ qkv_w, const float* __restrict__ proj_w,
                        const float* __restrict__ rpbt,
                        unsigned short* __restrict__ wqkvt, unsigned short* __restrict__ wprojt,
                        float* __restrict__ biasT) {
    int idx = blockIdx.x * 256 + threadIdx.x;
    if (idx < 49152) {                       // wqkvt[n][k] = qkv_w[k][n], bf16, (384,128)
        int n = idx >> 7, k = idx & 127;
        wqkvt[idx] = f2bf(qkv_w[k * 384 + n]);
    } else if (idx < 65536) {                // wprojt[n][k] = proj_w[k][n], bf16, (128,128)
        int j = idx - 49152;
        int n = j >> 7, k = j & 127;
        wprojt[j] = f2bf(proj_w[k * 128 + n]);
    } else if (idx < 65536 + 9604) {         // biasT[h][q][k] f32, (4,49,49)
        int j = idx - 65536;
        int h = j / 2401, qk = j % 2401;
        int q = qk / 49, k = qk % 49;
        int rel = (q / 7 - k / 7 + 6) * 13 + (q % 7 - k % 7 + 6);
        biasT[j] = rpbt[rel * 4 + h];
    }
}

// ---------------- fused window attention: one block per window ----------------
__global__ __launch_bounds__(512, 1) void wa_main(
    const float* __restrict__ x, const float* __restrict__ mask,
    const float* __restrict__ qkv_b, const float* __restrict__ proj_b,
    const unsigned short* __restrict__ wqkvt, const unsigned short* __restrict__ wprojt,
    const float* __restrict__ biasT, float* __restrict__ out)
{
    // strides padded to multiples of 8 elems (16B) for aligned ds_read_b128;
    // row-stride mod 128B gives 2-way bank aliasing only (free per m136).
    __shared__ unsigned short xb[64][136];     // x bf16 (A of qkv), later concat-X (A of proj)
    __shared__ unsigned short Qs[4][64][40];
    __shared__ unsigned short Ks[4][64][40];
    __shared__ unsigned short Vt[4][32][72];   // V transposed: [head][d][token]
    __shared__ unsigned short Ps[4][64][72];   // softmax probs bf16

    const int tid  = threadIdx.x;
    const int wv   = tid >> 6;
    const int lane = tid & 63;
    const int l15  = lane & 15;
    const int l4   = lane >> 4;
    const int b    = blockIdx.x;

    // ---- Phase 0: load x (49x128 f32) -> bf16 LDS, zero-pad rows 49..63 ----
    {
        const float* xp = x + (size_t)b * 6272;
        for (int i = tid; i < 1568; i += 512) {          // 1568 = 49*128/4
            int row = i >> 5;
            int c0  = (i & 31) << 2;
            f32x4 v = *reinterpret_cast<const f32x4*>(xp + i * 4);
            us4 sv;
            for (int j = 0; j < 4; ++j) sv[j] = f2bf(v[j]);
            *reinterpret_cast<us4*>(&xb[row][c0]) = sv;
        }
        us4 z = (us4)0;
        for (int i = tid; i < 510; i += 512) {           // 15 rows * 34 chunks
            int row = 49 + i / 34;
            int c0  = (i % 34) << 2;
            *reinterpret_cast<us4*>(&xb[row][c0]) = z;
        }
    }
    __syncthreads();

    // ---- Phase 1: qkv = x @ Wqkv + b  (each wave: 48 output cols) ----
    {
        bf16x8 afr[4][4];
        for (int m = 0; m < 4; ++m)
            for (int kk = 0; kk < 4; ++kk)
                afr[m][kk] = *reinterpret_cast<const bf16x8*>(&xb[m * 16 + l15][kk * 32 + l4 * 8]);
        f32x4 acc[4][3];
        for (int m = 0; m < 4; ++m)
            for (int n = 0; n < 3; ++n)
                acc[m][n] = (f32x4){0.f, 0.f, 0.f, 0.f};
        for (int n = 0; n < 3; ++n) {
            int col = wv * 48 + n * 16 + l15;
            const unsigned short* wp = wqkvt + col * 128 + l4 * 8;
            for (int kk = 0; kk < 4; ++kk) {
                bf16x8 bw = *reinterpret_cast<const bf16x8*>(wp + kk * 32);
                for (int m = 0; m < 4; ++m)
                    acc[m][n] = __builtin_amdgcn_mfma_f32_16x16x32_bf16(afr[m][kk], bw, acc[m][n], 0, 0, 0);
            }
        }
        for (int n = 0; n < 3; ++n) {
            int col  = wv * 48 + n * 16 + l15;
            float bv = qkv_b[col];
            int sec = col >> 7, c = col & 127, h = c >> 5, hc = c & 31;
            for (int m = 0; m < 4; ++m) {
                int row0 = m * 16 + l4 * 4;
                if (sec == 0) {
                    for (int r = 0; r < 4; ++r) Qs[h][row0 + r][hc] = f2bf(acc[m][n][r] + bv);
                } else if (sec == 1) {
                    for (int r = 0; r < 4; ++r) Ks[h][row0 + r][hc] = f2bf(acc[m][n][r] + bv);
                } else {
                    us4 pv;
                    for (int r = 0; r < 4; ++r) pv[r] = f2bf(acc[m][n][r] + bv);
                    *reinterpret_cast<us4*>(&Vt[h][hc][row0]) = pv;   // V transposed store
                }
            }
        }
    }
    __syncthreads();

    // ---- Phase 2: per-head attention. wave pair (h = wv>>1), half = rows 32*half.. ----
    {
        const int h = wv >> 1, half = wv & 1;
        bf16x8 qf[2];
        for (int ml = 0; ml < 2; ++ml)
            qf[ml] = *reinterpret_cast<const bf16x8*>(&Qs[h][(half * 2 + ml) * 16 + l15][l4 * 8]);
        f32x4 s[2][4];
        for (int ml = 0; ml < 2; ++ml)
            for (int n = 0; n < 4; ++n) s[ml][n] = (f32x4){0.f, 0.f, 0.f, 0.f};
        for (int n = 0; n < 4; ++n) {
            bf16x8 kf = *reinterpret_cast<const bf16x8*>(&Ks[h][n * 16 + l15][l4 * 8]);
            for (int ml = 0; ml < 2; ++ml)
                s[ml][n] = __builtin_amdgcn_mfma_f32_16x16x32_bf16(qf[ml], kf, s[ml][n], 0, 0, 0);
        }
        // softmax: each lane owns 8 rows x 4 cols; row-reduce across 16 lanes
        const float* bh = biasT + h * 2401;
        const float* mp = mask + (size_t)(b & 63) * 2401;
        for (int ml = 0; ml < 2; ++ml) {
            for (int r = 0; r < 4; ++r) {
                int row = (half * 2 + ml) * 16 + l4 * 4 + r;
                bool rowok = row < 49;
                float vals[4];
                for (int n = 0; n < 4; ++n) {
                    int cc = n * 16 + l15;
                    float lv = -1e30f;
                    if (rowok && cc < 49)
                        lv = s[ml][n][r] * SCALE + bh[row * 49 + cc] + mp[row * 49 + cc];
                    vals[n] = lv;
                }
                float mx = fmaxf(fmaxf(vals[0], vals[1]), fmaxf(vals[2], vals[3]));
                for (int d = 1; d < 16; d <<= 1) mx = fmaxf(mx, __shfl_xor(mx, d));
                float p[4], sum = 0.f;
                for (int n = 0; n < 4; ++n) { p[n] = __expf(vals[n] - mx); sum += p[n]; }
                for (int d = 1; d < 16; d <<= 1) sum += __shfl_xor(sum, d);
                float ri = 1.0f / sum;
                for (int n = 0; n < 4; ++n)
                    Ps[h][row][n * 16 + l15] = f2bf(p[n] * ri);   // cols>=49 get exact 0
            }
        }
        // PV: X[rows, d=32] = P[rows, 64] @ V[64, 32]
        bf16x8 pf[2][2];
        for (int ml = 0; ml < 2; ++ml)
            for (int kk = 0; kk < 2; ++kk)
                pf[ml][kk] = *reinterpret_cast<const bf16x8*>(&Ps[h][(half * 2 + ml) * 16 + l15][kk * 32 + l4 * 8]);
        f32x4 xacc[2][2];
        for (int ml = 0; ml < 2; ++ml)
            for (int n = 0; n < 2; ++n) xacc[ml][n] = (f32x4){0.f, 0.f, 0.f, 0.f};
        for (int n = 0; n < 2; ++n) {
            for (int kk = 0; kk < 2; ++kk) {
                bf16x8 vf = *reinterpret_cast<const bf16x8*>(&Vt[h][n * 16 + l15][kk * 32 + l4 * 8]);
                for (int ml = 0; ml < 2; ++ml)
                    xacc[ml][n] = __builtin_amdgcn_mfma_f32_16x16x32_bf16(pf[ml][kk], vf, xacc[ml][n], 0, 0, 0);
            }
        }
        // concat-X back into xb (bf16), layout [row][h*32 + d]
        for (int ml = 0; ml < 2; ++ml)
            for (int n = 0; n < 2; ++n)
                for (int r = 0; r < 4; ++r) {
                    int row = (half * 2 + ml) * 16 + l4 * 4 + r;
                    xb[row][h * 32 + n * 16 + l15] = f2bf(xacc[ml][n][r]);
                }
    }
    __syncthreads();

    // ---- Phase 3: out = X @ Wproj + b  (each wave: 16 cols) ----
    {
        bf16x8 a2[4][4];
        for (int m = 0; m < 4; ++m)
            for (int kk = 0; kk < 4; ++kk)
                a2[m][kk] = *reinterpret_cast<const bf16x8*>(&xb[m * 16 + l15][kk * 32 + l4 * 8]);
        f32x4 o[4];
        for (int m = 0; m < 4; ++m) o[m] = (f32x4){0.f, 0.f, 0.f, 0.f};
        int col = wv * 16 + l15;
        const unsigned short* wp = wprojt + col * 128 + l4 * 8;
        for (int kk = 0; kk < 4; ++kk) {
            bf16x8 bw = *reinterpret_cast<const bf16x8*>(wp + kk * 32);
            for (int m = 0; m < 4; ++m)
                o[m] = __builtin_amdgcn_mfma_f32_16x16x32_bf16(a2[m][kk], bw, o[m], 0, 0, 0);
        }
        float pb = proj_b[col];
        float* op = out + (size_t)b * 6272 + col;
        for (int m = 0; m < 4; ++m)
            for (int r = 0; r < 4; ++r) {
                int row = m * 16 + l4 * 4 + r;
                if (row < 49) op[row * 128] = o[m][r] + pb;
            }
    }
}

extern "C" void kernel_launch(void* const* d_in, const int* in_sizes, int n_in,
                              void* d_out, int out_size, void* d_ws, size_t ws_size,
                              hipStream_t stream) {
    const float* x      = (const float*)d_in[0];
    const float* mask   = (const float*)d_in[1];
    const float* qkv_w  = (const float*)d_in[2];
    const float* qkv_b  = (const float*)d_in[3];
    const float* proj_w = (const float*)d_in[4];
    const float* proj_b = (const float*)d_in[5];
    const float* rpbt   = (const float*)d_in[6];
    float* out = (float*)d_out;

    unsigned short* wqkvt  = (unsigned short*)d_ws;                       // 98304 B
    unsigned short* wprojt = (unsigned short*)((char*)d_ws + 98304);      // 32768 B
    float*          biasT  = (float*)((char*)d_ws + 98304 + 32768);       // 38416 B

    wa_prep<<<294, 256, 0, stream>>>(qkv_w, proj_w, rpbt, wqkvt, wprojt, biasT);
    wa_main<<<4096, 512, 0, stream>>>(x, mask, qkv_b, proj_b, wqkvt, wprojt, biasT, out);
}

// Round 2
// 124.768 us; speedup vs baseline: 1.7565x; 1.7565x over previous
//
#include <hip/hip_runtime.h>

typedef __bf16 bf16x8 __attribute__((ext_vector_type(8)));
typedef float f32x4 __attribute__((ext_vector_type(4)));
typedef unsigned short us4 __attribute__((ext_vector_type(4)));
typedef short s4 __attribute__((ext_vector_type(4)));

#define SCALE 0.17677669529663687f

__device__ __forceinline__ unsigned short f2bf(float f) {
    union { float f; unsigned u; } v; v.f = f;
    unsigned r = v.u + 0x7FFFu + ((v.u >> 16) & 1u);
    return (unsigned short)(r >> 16);
}

// ---------------- prep: transpose+bf16 weights, build (bias[+mask]) table ----------------
__global__ void wa_prep(const float* __restrict__ qkv_w, const float* __restrict__ proj_w,
                        const float* __restrict__ rpbt, const float* __restrict__ mask,
                        unsigned short* __restrict__ wqkvt, unsigned short* __restrict__ wprojt,
                        float* __restrict__ tab, int use_bm) {
    int idx = blockIdx.x * 256 + threadIdx.x;
    if (idx < 49152) {                       // wqkvt[n][k] = qkv_w[k][n], bf16, (384,128)
        int n = idx >> 7, k = idx & 127;
        wqkvt[idx] = f2bf(qkv_w[k * 384 + n]);
    } else if (idx < 65536) {                // wprojt[n][k] = proj_w[k][n], bf16, (128,128)
        int j = idx - 49152;
        int n = j >> 7, k = j & 127;
        wprojt[j] = f2bf(proj_w[k * 128 + n]);
    } else {
        int j = idx - 65536;
        if (use_bm) {
            // BM[w][h][q][52] = bias + mask (padded k-stride 52 for aligned f32x4)
            if (j < 64 * 4 * 49 * 52) {
                int k = j % 52; int t = j / 52; int q = t % 49; t /= 49;
                int h = t & 3, w = t >> 2;
                float v = 0.f;
                if (k < 49) {
                    int rel = (q / 7 - k / 7 + 6) * 13 + (q % 7 - k % 7 + 6);
                    v = rpbt[rel * 4 + h] + mask[w * 2401 + q * 49 + k];
                }
                tab[j] = v;
            }
        } else {
            // biasP[h][q][52]
            if (j < 4 * 49 * 52) {
                int k = j % 52; int t = j / 52; int q = t % 49; int h = t / 49;
                float v = 0.f;
                if (k < 49) {
                    int rel = (q / 7 - k / 7 + 6) * 13 + (q % 7 - k % 7 + 6);
                    v = rpbt[rel * 4 + h];
                }
                tab[j] = v;
            }
        }
    }
}

// ---------------- fused window attention: one block per window, 2 blocks/CU ----------------
__global__ __launch_bounds__(512, 4) void wa_main(
    const float* __restrict__ x, const float* __restrict__ mask,
    const float* __restrict__ qkv_b, const float* __restrict__ proj_b,
    const unsigned short* __restrict__ wqkvt, const unsigned short* __restrict__ wprojt,
    const float* __restrict__ tab, int use_bm, float* __restrict__ out)
{
    __shared__ unsigned short xb[64][136];     // x bf16 (A of qkv GEMM)
    __shared__ unsigned short Qs[4][64][40];   // Q per head; reused as concat-X after attention
    __shared__ unsigned short Ks[4][64][40];
    __shared__ unsigned short Vt[4][32][72];   // V transposed: [head][d][token]

    const int tid  = threadIdx.x;
    const int wv   = tid >> 6;
    const int lane = tid & 63;
    const int l15  = lane & 15;
    const int l4   = lane >> 4;
    const int b    = blockIdx.x;

    // ---- Phase 0: load x (49x128 f32) -> bf16 LDS, zero-pad rows 49..63 ----
    {
        const float* xp = x + (size_t)b * 6272;
        for (int i = tid; i < 1568; i += 512) {          // 1568 = 49*128/4
            int row = i >> 5;
            int c0  = (i & 31) << 2;
            f32x4 v = *reinterpret_cast<const f32x4*>(xp + i * 4);
            us4 sv;
            for (int j = 0; j < 4; ++j) sv[j] = f2bf(v[j]);
            *reinterpret_cast<us4*>(&xb[row][c0]) = sv;
        }
        us4 z = (us4)0;
        for (int i = tid; i < 510; i += 512) {           // 15 rows * 34 chunks (covers 136 cols)
            int row = 49 + i / 34;
            int c0  = (i % 34) << 2;
            *reinterpret_cast<us4*>(&xb[row][c0]) = z;
        }
    }
    __syncthreads();

    // ---- Phase 1: qkv = x @ Wqkv + b  (each wave: 48 output cols) ----
    {
        bf16x8 afr[4][4];
        for (int m = 0; m < 4; ++m)
            for (int kk = 0; kk < 4; ++kk)
                afr[m][kk] = *reinterpret_cast<const bf16x8*>(&xb[m * 16 + l15][kk * 32 + l4 * 8]);
        f32x4 acc[4][3];
        for (int m = 0; m < 4; ++m)
            for (int n = 0; n < 3; ++n)
                acc[m][n] = (f32x4){0.f, 0.f, 0.f, 0.f};
        for (int n = 0; n < 3; ++n) {
            int col = wv * 48 + n * 16 + l15;
            const unsigned short* wp = wqkvt + col * 128 + l4 * 8;
            for (int kk = 0; kk < 4; ++kk) {
                bf16x8 bw = *reinterpret_cast<const bf16x8*>(wp + kk * 32);
                for (int m = 0; m < 4; ++m)
                    acc[m][n] = __builtin_amdgcn_mfma_f32_16x16x32_bf16(afr[m][kk], bw, acc[m][n], 0, 0, 0);
            }
        }
        for (int n = 0; n < 3; ++n) {
            int col  = wv * 48 + n * 16 + l15;
            float bv = qkv_b[col];
            int sec = col >> 7, c = col & 127, h = c >> 5, hc = c & 31;
            for (int m = 0; m < 4; ++m) {
                int row0 = m * 16 + l4 * 4;
                if (sec == 0) {
                    for (int r = 0; r < 4; ++r) Qs[h][row0 + r][hc] = f2bf(acc[m][n][r] + bv);
                } else if (sec == 1) {
                    for (int r = 0; r < 4; ++r) Ks[h][row0 + r][hc] = f2bf(acc[m][n][r] + bv);
                } else {
                    us4 pv;
                    for (int r = 0; r < 4; ++r) pv[r] = f2bf(acc[m][n][r] + bv);
                    *reinterpret_cast<us4*>(&Vt[h][hc][row0]) = pv;   // V transposed store
                }
            }
        }
    }
    __syncthreads();

    // ---- Phase 2: attention, swapped S^T = K·Q^T so P lands in-register in A-frag layout ----
    {
        const int h = wv >> 1, half = wv & 1;
        bf16x8 kf[4];
        for (int n = 0; n < 4; ++n)
            kf[n] = *reinterpret_cast<const bf16x8*>(&Ks[h][n * 16 + l15][l4 * 8]);
        bf16x8 qf[2];
        for (int m = 0; m < 2; ++m)
            qf[m] = *reinterpret_cast<const bf16x8*>(&Qs[h][(half * 2 + m) * 16 + l15][l4 * 8]);
        f32x4 s[2][4];
        for (int m = 0; m < 2; ++m)
            for (int n = 0; n < 4; ++n) s[m][n] = (f32x4){0.f, 0.f, 0.f, 0.f};
        for (int m = 0; m < 2; ++m)
            for (int n = 0; n < 4; ++n)
                s[m][n] = __builtin_amdgcn_mfma_f32_16x16x32_bf16(kf[n], qf[m], s[m][n], 0, 0, 0);
        // lane (l15,l4) now holds S[q = mtile*16+l15][k = n*16 + l4*4 + r]

        const float* tp = tab + (size_t)(use_bm ? ((b & 63) * 4 + h) : h) * (49 * 52);
        const float* mp = mask + (size_t)(b & 63) * 2401;

        s4 pf[2][4];
        for (int m = 0; m < 2; ++m) {
            int qg = (half * 2 + m) * 16 + l15;
            bool qok = qg < 49;
            int qc = qok ? qg : 48;
            float vals[4][4];
            for (int n = 0; n < 4; ++n) {
                f32x4 t = *reinterpret_cast<const f32x4*>(tp + qc * 52 + n * 16 + l4 * 4);
                for (int r = 0; r < 4; ++r) {
                    int k = n * 16 + l4 * 4 + r;
                    float lv = -1e30f;
                    if (qok && k < 49) {
                        float add = t[r];
                        if (!use_bm) add += mp[qg * 49 + k];
                        lv = s[m][n][r] * SCALE + add;
                    }
                    vals[n][r] = lv;
                }
            }
            float mx = -1e30f;
            for (int n = 0; n < 4; ++n)
                for (int r = 0; r < 4; ++r) mx = fmaxf(mx, vals[n][r]);
            mx = fmaxf(mx, __shfl_xor(mx, 16));
            mx = fmaxf(mx, __shfl_xor(mx, 32));
            float p[4][4], sum = 0.f;
            for (int n = 0; n < 4; ++n)
                for (int r = 0; r < 4; ++r) { p[n][r] = __expf(vals[n][r] - mx); sum += p[n][r]; }
            sum += __shfl_xor(sum, 16);
            sum += __shfl_xor(sum, 32);
            float ri = 1.0f / sum;
            for (int n = 0; n < 4; ++n) {
                us4 pk;
                for (int r = 0; r < 4; ++r) pk[r] = f2bf(p[n][r] * ri);
                union { us4 u; s4 v; } cv; cv.u = pk;
                pf[m][n] = cv.v;
            }
        }
        // PV via 16x16x16: A = P (in-register), B = V^T columns
        f32x4 xacc[2][2];
        for (int m = 0; m < 2; ++m)
            for (int dt = 0; dt < 2; ++dt) xacc[m][dt] = (f32x4){0.f, 0.f, 0.f, 0.f};
        for (int n = 0; n < 4; ++n)
            for (int dt = 0; dt < 2; ++dt) {
                s4 vf = *reinterpret_cast<const s4*>(&Vt[h][dt * 16 + l15][n * 16 + l4 * 4]);
                for (int m = 0; m < 2; ++m)
                    xacc[m][dt] = __builtin_amdgcn_mfma_f32_16x16x16bf16_1k(pf[m][n], vf, xacc[m][dt], 0, 0, 0);
            }
        // concat-X per-head into Qs[h] (Q is dead; rows written == rows this wave owns)
        for (int m = 0; m < 2; ++m)
            for (int dt = 0; dt < 2; ++dt)
                for (int r = 0; r < 4; ++r)
                    Qs[h][(half * 2 + m) * 16 + l4 * 4 + r][dt * 16 + l15] = f2bf(xacc[m][dt][r]);
    }
    __syncthreads();

    // ---- Phase 3: out = X @ Wproj + b  (each wave: 16 cols; A read per-head from Qs) ----
    {
        bf16x8 a2[4][4];
        for (int m = 0; m < 4; ++m)
            for (int kk = 0; kk < 4; ++kk)
                a2[m][kk] = *reinterpret_cast<const bf16x8*>(&Qs[kk][m * 16 + l15][l4 * 8]);
        f32x4 o[4];
        for (int m = 0; m < 4; ++m) o[m] = (f32x4){0.f, 0.f, 0.f, 0.f};
        int col = wv * 16 + l15;
        const unsigned short* wp = wprojt + col * 128 + l4 * 8;
        for (int kk = 0; kk < 4; ++kk) {
            bf16x8 bw = *reinterpret_cast<const bf16x8*>(wp + kk * 32);
            for (int m = 0; m < 4; ++m)
                o[m] = __builtin_amdgcn_mfma_f32_16x16x32_bf16(a2[m][kk], bw, o[m], 0, 0, 0);
        }
        float pb = proj_b[col];
        float* op = out + (size_t)b * 6272 + col;
        for (int m = 0; m < 4; ++m)
            for (int r = 0; r < 4; ++r) {
                int row = m * 16 + l4 * 4 + r;
                if (row < 49) op[row * 128] = o[m][r] + pb;
            }
    }
}

extern "C" void kernel_launch(void* const* d_in, const int* in_sizes, int n_in,
                              void* d_out, int out_size, void* d_ws, size_t ws_size,
                              hipStream_t stream) {
    const float* x      = (const float*)d_in[0];
    const float* mask   = (const float*)d_in[1];
    const float* qkv_w  = (const float*)d_in[2];
    const float* qkv_b  = (const float*)d_in[3];
    const float* proj_w = (const float*)d_in[4];
    const float* proj_b = (const float*)d_in[5];
    const float* rpbt   = (const float*)d_in[6];
    float* out = (float*)d_out;

    unsigned short* wqkvt  = (unsigned short*)d_ws;                       // 98304 B
    unsigned short* wprojt = (unsigned short*)((char*)d_ws + 98304);      // 32768 B
    float*          tab    = (float*)((char*)d_ws + 131072);

    const size_t needed_big = 131072 + (size_t)64 * 4 * 49 * 52 * 4;      // ~2.74 MB
    int use_bm = (ws_size >= needed_big) ? 1 : 0;
    int total  = 65536 + (use_bm ? 64 * 4 * 49 * 52 : 4 * 49 * 52);

    wa_prep<<<(total + 255) / 256, 256, 0, stream>>>(qkv_w, proj_w, rpbt, mask, wqkvt, wprojt, tab, use_bm);
    wa_main<<<4096, 512, 0, stream>>>(x, mask, qkv_b, proj_b, wqkvt, wprojt, tab, use_bm, out);
}